// Round 10
// baseline (73.714 us; speedup 1.0000x reference)
//
#include <hip/hip_runtime.h>

#define NC 1024
#define DY 16
#define NG 65536

#define SZ_WXH (256 * 1024)        // h16 per m: [i][k] plain
#define SZ_WYA (16 * 32 * 64 * 8)  // h16 per m: [jt][ks][lane][jj] A-frag order
#define SZ_YTB (32 * 64 * 8)       // h16 per m: [ks][lane][jj]     B-frag order

typedef float v4f __attribute__((ext_vector_type(4)));
typedef _Float16 h8 __attribute__((ext_vector_type(8)));

// ---- K1: table builder. 8 exps (or cvts) + one 16B store per thread. ----
__global__ __launch_bounds__(256) void setconv_tables(
    const float* __restrict__ xc, const float* __restrict__ yc,
    const float* __restrict__ lsp,
    _Float16* __restrict__ WXh, _Float16* __restrict__ WYA,
    _Float16* __restrict__ YTB, int m)
{
    const int t  = blockIdx.x * 256 + threadIdx.x;
    const int T0 = m * (SZ_WXH / 8);
    const int T1 = T0 + m * (SZ_WYA / 8);
    const int T2 = T1 + m * (SZ_YTB / 8);
    if (t >= T2) return;

    if (t < T0) {
        // WXh[m][i][k] plain layout
        const float l0 = 1e-5f + __logf(1.0f + __expf(lsp[0]));
        const float s0 = 0.84932184f / l0;          // sqrt(log2e/2)/l
        const int mm  = t >> 15;
        const int rem = t & 32767;
        const int i   = rem >> 7;
        const int k0  = (rem & 127) << 3;
        const float g = (1.0f + (float)(i - 128) * 0.015625f) * s0;
        h8 o;
#pragma unroll
        for (int jj = 0; jj < 8; ++jj) {
            const float u = g - xc[((size_t)(mm * NC + k0 + jj)) << 1] * s0;
            o[jj] = (_Float16)__builtin_amdgcn_exp2f(-u * u);
        }
        *(h8*)&WXh[(size_t)t * 8] = o;
    } else if (t < T1) {
        // WYA[m][jt][ks][lane][jj] A-fragment order
        const float l1 = 1e-5f + __logf(1.0f + __expf(lsp[1]));
        const float s1 = 0.84932184f / l1;
        const int tt   = t - T0;
        const int mm   = tt >> 15;
        const int rem  = tt & 32767;
        const int jt   = rem >> 11;
        const int ks   = (rem >> 6) & 31;
        const int lane = rem & 63;
        const int j    = jt * 16 + (lane & 15);
        const int k0   = ks * 32 + ((lane >> 4) << 3);
        const float g  = (1.0f + (float)(j - 128) * 0.015625f) * s1;
        h8 o;
#pragma unroll
        for (int jj = 0; jj < 8; ++jj) {
            const float u = g - xc[(((size_t)(mm * NC + k0 + jj)) << 1) + 1] * s1;
            o[jj] = (_Float16)__builtin_amdgcn_exp2f(-u * u);
        }
        *(h8*)&WYA[(size_t)tt * 8] = o;
    } else {
        // YTB[m][ks][lane][jj] B-fragment order (ch = lane&15)
        const int tt   = t - T1;
        const int mm   = tt >> 11;
        const int rem  = tt & 2047;
        const int ks   = rem >> 6;
        const int lane = rem & 63;
        const int ch   = lane & 15;
        const int k0   = ks * 32 + ((lane >> 4) << 3);
        h8 o;
#pragma unroll
        for (int jj = 0; jj < 8; ++jj)
            o[jj] = (_Float16)yc[(((size_t)(mm * NC + k0 + jj)) << 4) + ch];
        *(h8*)&YTB[(size_t)tt * 8] = o;
    }
}

// ---- K2: pure GEMM. Block = 4 i-rows x 64 j (4 waves). Prologue is only
// linear float4 copies; per ks: 1 wy global dwordx4 (L2) + 1 yt ds_read_b128
// + 4 quad-broadcast wx + 16 pk_mul + 8 MFMA (4 data + 4 ones-density). ----
__global__ __launch_bounds__(256, 2) void setconv_main(
    const _Float16* __restrict__ WXh, const _Float16* __restrict__ WYA,
    const _Float16* __restrict__ YTB,
    float* __restrict__ out_grid,   // [m, 256, 256, 2]
    float* __restrict__ out_z)      // [m, 256, 256, 17]
{
    __shared__ __align__(16) _Float16 ytb[SZ_YTB];   // 32 KB
    __shared__ __align__(16) _Float16 wx4[4][NC];    // 8 KB

    const int mi   = blockIdx.y;
    const int bx   = blockIdx.x;     // 0..255
    const int ig   = bx >> 2;        // 0..63
    const int jg   = bx & 3;
    const int tid  = threadIdx.x;
    const int wave = tid >> 6;
    const int lane = tid & 63;
    const int q    = lane >> 4;
    const int r    = lane & 15;
    const int jt   = jg * 4 + wave;  // 0..15
    const int i0   = ig * 4;

    // out_grid: this block's 4x64 tile, one point per thread (coalesced)
    {
        const int g  = (i0 + (tid >> 6)) * 256 + jg * 64 + (tid & 63);
        const float gx = 1.0f + (float)((g >> 8) - 128) * 0.015625f;
        const float gy = 1.0f + (float)((g & 255) - 128) * 0.015625f;
        ((float2*)out_grid)[(size_t)mi * NG + g] = make_float2(gx, gy);
    }

    // prologue: linear copies only
    {
        const float4* wsrc = (const float4*)(WXh + ((size_t)mi * 256 + i0) * 1024);
        float4* wdst = (float4*)wx4;
        wdst[tid]       = wsrc[tid];          // 8 KB
        wdst[tid + 256] = wsrc[tid + 256];
        const float4* src = (const float4*)(YTB + (size_t)mi * SZ_YTB);
        float4* dst = (float4*)ytb;           // 32 KB
#pragma unroll
        for (int tt = 0; tt < 8; ++tt) dst[tid + 256 * tt] = src[tid + 256 * tt];
    }
    __syncthreads();

    const _Float16* wyp = WYA + (((size_t)mi * 16 + jt) * 32 * 64 + lane) * 8;

    h8 ones;
#pragma unroll
    for (int e = 0; e < 8; ++e) ones[e] = (_Float16)1.0f;

    v4f accD[4], accS[4];
#pragma unroll
    for (int ii = 0; ii < 4; ++ii) {
        accD[ii] = (v4f){0.f, 0.f, 0.f, 0.f};
        accS[ii] = (v4f){0.f, 0.f, 0.f, 0.f};
    }

#pragma unroll 4
    for (int ks = 0; ks < 32; ++ks) {
        const h8 wy = *(const h8*)(wyp + (size_t)ks * 512);            // global dwordx4
        const h8 yt = *(const h8*)&ytb[((size_t)ks * 64 + lane) * 8];  // ds_read_b128
#pragma unroll
        for (int ii = 0; ii < 4; ++ii) {
            const h8 wx = *(const h8*)&wx4[ii][ks * 32 + q * 8];       // quad-broadcast
            const h8 a  = wy * wx;                                     // 4x v_pk_mul_f16
            accD[ii] = __builtin_amdgcn_mfma_f32_16x16x32_f16(a, yt,   accD[ii], 0, 0, 0);
            accS[ii] = __builtin_amdgcn_mfma_f32_16x16x32_f16(a, ones, accS[ii], 0, 0, 0);
        }
    }

    // C/D: col(lane&15)=channel, row(q*4+reg)=j (validated r3-r9)
#pragma unroll
    for (int ii = 0; ii < 4; ++ii) {
        float* __restrict__ oz =
            out_z + ((size_t)mi * NG + (size_t)(i0 + ii) * 256 + jt * 16) * 17;
#pragma unroll
        for (int reg = 0; reg < 4; ++reg) {
            const int row = q * 4 + reg;
            oz[(size_t)row * 17 + r] = accD[ii][reg];
            if (r == 0) oz[(size_t)row * 17 + 16] = accS[ii][reg];
        }
    }
}

extern "C" void kernel_launch(void* const* d_in, const int* in_sizes, int n_in,
                              void* d_out, int out_size, void* d_ws, size_t ws_size,
                              hipStream_t stream) {
    const float* xc  = (const float*)d_in[0];   // [m, 1024, 2]
    const float* yc  = (const float*)d_in[1];   // [m, 1024, 16]
    // d_in[2] = xt — unused by the reference output
    const float* lsp = (const float*)d_in[3];   // [2]

    int m = in_sizes[0] / (NC * 2);             // = 2

    float* out_grid = (float*)d_out;
    float* out_z    = (float*)d_out + (size_t)m * NG * 2;

    _Float16* WXh = (_Float16*)d_ws;
    _Float16* WYA = WXh + (size_t)m * SZ_WXH;
    _Float16* YTB = WYA + (size_t)m * SZ_WYA;

    const int total1 = m * (SZ_WXH / 8 + SZ_WYA / 8 + SZ_YTB / 8);
    hipLaunchKernelGGL(setconv_tables, dim3((total1 + 255) / 256), dim3(256),
                       0, stream, xc, yc, lsp, WXh, WYA, YTB, m);

    hipLaunchKernelGGL(setconv_main, dim3(256, m), dim3(256), 0, stream,
                       WXh, WYA, YTB, out_grid, out_z);
}